// Round 3
// baseline (388.218 us; speedup 1.0000x reference)
//
#include <hip/hip_runtime.h>

#define BB 2
#define SS 2048
#define EE 1024
#define HH 16
#define DD 64

typedef unsigned short u16;
typedef float f4 __attribute__((ext_vector_type(4)));
typedef __bf16 b8 __attribute__((ext_vector_type(8)));
typedef short s8i __attribute__((ext_vector_type(8)));
typedef u16 u16x4 __attribute__((ext_vector_type(4)));

__device__ inline u16 f2b(float f) {
  unsigned u = __builtin_bit_cast(unsigned, f);
  unsigned r = (u + 0x7fffu + ((u >> 16) & 1u)) >> 16;
  return (u16)r;
}

// ---------------- prep kernels ----------------
__global__ void castx(const float* __restrict__ x, u16* __restrict__ xb) {
  const int N4 = BB * SS * EE / 4;
  for (int i = blockIdx.x * blockDim.x + threadIdx.x; i < N4;
       i += gridDim.x * blockDim.x) {
    f4 v = ((const f4*)x)[i];
    u16x4 o;
    for (int j = 0; j < 4; ++j) o[j] = f2b(v[j]);
    ((u16x4*)xb)[i] = o;
  }
}

// Wt[(qkv*1024 + h*64 + d)][e] = Wqkv[h][e][d]  — LDS tile transpose
__global__ __launch_bounds__(256) void transW(const float* __restrict__ Wq,
                                              const float* __restrict__ Wk,
                                              const float* __restrict__ Wv,
                                              u16* __restrict__ Wt) {
  __shared__ float tile[64][65];
  int t = threadIdx.x;
  int e0 = blockIdx.x * 64;
  int y = blockIdx.y;          // 0..47
  int qkv = y >> 4, h = y & 15;
  const float* W = (qkv == 0) ? Wq : (qkv == 1) ? Wk : Wv;
  for (int p = 0; p < 16; ++p) {
    int i = p * 4 + (t >> 6), d = t & 63;
    tile[i][d] = W[((size_t)h * EE + e0 + i) * DD + d];
  }
  __syncthreads();
  for (int p = 0; p < 16; ++p) {
    int d = p * 4 + (t >> 6), i = t & 63;
    Wt[((size_t)qkv * 1024 + h * 64 + d) * EE + e0 + i] = f2b(tile[i][d]);
  }
}

// Wot[c][e] = Wo[e][c]
__global__ __launch_bounds__(256) void transWo(const float* __restrict__ Wo,
                                               u16* __restrict__ Wot) {
  __shared__ float tile[64][65];
  int t = threadIdx.x;
  int e0 = blockIdx.x * 64, c0 = blockIdx.y * 64;
  for (int p = 0; p < 16; ++p) {
    int i = p * 4 + (t >> 6), j = t & 63;
    tile[i][j] = Wo[(size_t)(e0 + i) * (HH * DD) + c0 + j];
  }
  __syncthreads();
  for (int p = 0; p < 16; ++p) {
    int j = p * 4 + (t >> 6), i = t & 63;
    Wot[(size_t)(c0 + j) * EE + e0 + i] = f2b(tile[i][j]);
  }
}

// ---------------- 128x128 bf16 MFMA GEMM, global_load_lds staging -------------
// MODE 0: C -> Q(scaled 1/8)/K bf16 [B,H,S,D], V bf16 [B,H,D,S] (transposed)
// MODE 1: C -> fp32 out [4096,1024] + bo
template <int MODE>
__global__ __launch_bounds__(256) void gemm128(
    const u16* __restrict__ A, const u16* __restrict__ Bm,
    u16* __restrict__ Qo, u16* __restrict__ Ko, u16* __restrict__ Vo,
    const float* __restrict__ bq, const float* __restrict__ bk,
    const float* __restrict__ bv,
    float* __restrict__ Co, const float* __restrict__ bo) {
  const int K = 1024;
  __shared__ u16 As[128 * 32];
  __shared__ u16 Bs[128 * 32];
  int t = threadIdx.x;
  int lane = t & 63, w = t >> 6;
  int wr = w >> 1, wc = w & 1;
  int lr = lane & 15, lg = lane >> 4;
  int m0 = blockIdx.y * 128, n0 = blockIdx.x * 128;

  f4 acc[4][4];
  const f4 z4 = {0.f, 0.f, 0.f, 0.f};
  for (int mi = 0; mi < 4; ++mi)
    for (int ni = 0; ni < 4; ++ni) acc[mi][ni] = z4;

  // staging map: 16B chunk c at LDS byte c*16; c = row*4 + slot, row-major [128][32]
  int r0 = t >> 2, s0 = t & 3;
  const u16* ga0 = A + (size_t)(m0 + r0) * K + s0 * 8;
  const u16* gb0 = Bm + (size_t)(n0 + r0) * K + s0 * 8;
  u16* la0 = As + w * 512;        // wave-uniform base, lane*16B implicit
  u16* la1 = As + 2048 + w * 512;
  u16* lb0 = Bs + w * 512;
  u16* lb1 = Bs + 2048 + w * 512;

  for (int ks = 0; ks < K / 32; ++ks) {
    int k0 = ks * 32;
    __builtin_amdgcn_global_load_lds(
        (const __attribute__((address_space(1))) void*)(ga0 + k0),
        (__attribute__((address_space(3))) void*)la0, 16, 0, 0);
    __builtin_amdgcn_global_load_lds(
        (const __attribute__((address_space(1))) void*)(ga0 + 64 * K + k0),
        (__attribute__((address_space(3))) void*)la1, 16, 0, 0);
    __builtin_amdgcn_global_load_lds(
        (const __attribute__((address_space(1))) void*)(gb0 + k0),
        (__attribute__((address_space(3))) void*)lb0, 16, 0, 0);
    __builtin_amdgcn_global_load_lds(
        (const __attribute__((address_space(1))) void*)(gb0 + 64 * K + k0),
        (__attribute__((address_space(3))) void*)lb1, 16, 0, 0);
    __syncthreads();
    b8 af[4], bf[4];
    for (int mi = 0; mi < 4; ++mi)
      af[mi] = *(const b8*)&As[(wr * 64 + mi * 16 + lr) * 32 + lg * 8];
    for (int ni = 0; ni < 4; ++ni)
      bf[ni] = *(const b8*)&Bs[(wc * 64 + ni * 16 + lr) * 32 + lg * 8];
    for (int mi = 0; mi < 4; ++mi)
      for (int ni = 0; ni < 4; ++ni)
        acc[mi][ni] = __builtin_amdgcn_mfma_f32_16x16x32_bf16(af[mi], bf[ni],
                                                              acc[mi][ni], 0, 0, 0);
    __syncthreads();
  }

  for (int mi = 0; mi < 4; ++mi)
    for (int ni = 0; ni < 4; ++ni)
      for (int r = 0; r < 4; ++r) {
        int m_g = m0 + wr * 64 + mi * 16 + lg * 4 + r;
        int n_g = n0 + wc * 64 + ni * 16 + lr;
        float v = acc[mi][ni][r];
        if (MODE == 0) {
          int qkv = n_g >> 10, hd = n_g & 1023;
          const float* bias = (qkv == 0) ? bq : (qkv == 1) ? bk : bv;
          v += bias[hd];
          int b = m_g >> 11, s = m_g & 2047;
          int h = hd >> 6, d = hd & 63;
          if (qkv == 0) {
            Qo[(((size_t)b * HH + h) * SS + s) * DD + d] = f2b(v * 0.125f);
          } else if (qkv == 1) {
            Ko[(((size_t)b * HH + h) * SS + s) * DD + d] = f2b(v);
          } else {  // V stored transposed: [B,H,D,S]
            Vo[(((size_t)b * HH + h) * DD + d) * SS + s] = f2b(v);
          }
        } else {
          Co[(size_t)m_g * 1024 + n_g] = v + bo[n_g];
        }
      }
}

// ---------------- flash attention (causal), no K/V staging, KVBLK=64 ---------
#define PST 72  // P LDS row stride (u16): 16B-aligned rows, conflict-light
__global__ __launch_bounds__(256) void fattn(const u16* __restrict__ Qb,
                                             const u16* __restrict__ Kb,
                                             const u16* __restrict__ VTb,
                                             u16* __restrict__ AO) {
  __shared__ u16 Pl[4][16 * PST];

  int t = threadIdx.x, lane = t & 63, w = t >> 6;
  int lr = lane & 15, lg = lane >> 4;
  int qt = (gridDim.x - 1) - blockIdx.x;  // heavy blocks first
  int bh = blockIdx.y;
  int b = bh >> 4, h = bh & 15;
  int qbase = qt * 64;
  size_t base = (size_t)bh * SS * DD;  // same extent for K and VT

  // Q fragments (pre-scaled by 1/8): row = qbase + w*16 + lr
  const u16* qp = Qb + base + (size_t)(qbase + w * 16 + lr) * DD;
  b8 qf0 = *(const b8*)(qp + lg * 8);
  b8 qf1 = *(const b8*)(qp + 32 + lg * 8);

  const f4 z4 = {0.f, 0.f, 0.f, 0.f};
  f4 o[4];
  for (int i = 0; i < 4; ++i) o[i] = z4;
  float mrow[4], lsum[4];
  for (int r = 0; r < 4; ++r) { mrow[r] = -1e30f; lsum[r] = 0.f; }

  int qg = qbase + w * 16 + lg * 4;
  for (int kt = 0; kt <= qt; ++kt) {
    int kv0 = kt * 64;
    const u16* kp = Kb + base + (size_t)kv0 * DD;

    // S = Q K^T : 4 col-tiles of 16, K read direct from global (L2-resident)
    f4 sa[4];
    for (int n = 0; n < 4; ++n) sa[n] = z4;
    for (int n = 0; n < 4; ++n) {
      b8 kf0 = *(const b8*)(kp + (size_t)(n * 16 + lr) * DD + lg * 8);
      b8 kf1 = *(const b8*)(kp + (size_t)(n * 16 + lr) * DD + 32 + lg * 8);
      sa[n] = __builtin_amdgcn_mfma_f32_16x16x32_bf16(qf0, kf0, sa[n], 0, 0, 0);
      sa[n] = __builtin_amdgcn_mfma_f32_16x16x32_bf16(qf1, kf1, sa[n], 0, 0, 0);
    }

    // online softmax (rows in lanes same-lg; reduce over lr via xor 1,2,4,8)
    bool diag = (kt == qt);
    float scl[4];
    for (int r = 0; r < 4; ++r) {
      float v0 = sa[0][r], v1 = sa[1][r], v2 = sa[2][r], v3 = sa[3][r];
      if (diag) {
        int q = qg + r;
        if (kv0 + lr > q) v0 = -1e30f;
        if (kv0 + 16 + lr > q) v1 = -1e30f;
        if (kv0 + 32 + lr > q) v2 = -1e30f;
        if (kv0 + 48 + lr > q) v3 = -1e30f;
      }
      float mx = fmaxf(fmaxf(v0, v1), fmaxf(v2, v3));
      mx = fmaxf(mx, __shfl_xor(mx, 1));
      mx = fmaxf(mx, __shfl_xor(mx, 2));
      mx = fmaxf(mx, __shfl_xor(mx, 4));
      mx = fmaxf(mx, __shfl_xor(mx, 8));
      float mn = fmaxf(mrow[r], mx);
      float sc = __expf(mrow[r] - mn);
      float p0 = __expf(v0 - mn), p1 = __expf(v1 - mn);
      float p2 = __expf(v2 - mn), p3 = __expf(v3 - mn);
      float ps = (p0 + p1) + (p2 + p3);
      ps += __shfl_xor(ps, 1);
      ps += __shfl_xor(ps, 2);
      ps += __shfl_xor(ps, 4);
      ps += __shfl_xor(ps, 8);
      lsum[r] = lsum[r] * sc + ps;
      mrow[r] = mn;
      scl[r] = sc;
      int prow = (lg * 4 + r) * PST;
      Pl[w][prow + lr] = f2b(p0);
      Pl[w][prow + 16 + lr] = f2b(p1);
      Pl[w][prow + 32 + lr] = f2b(p2);
      Pl[w][prow + 48 + lr] = f2b(p3);
    }
    for (int n = 0; n < 4; ++n) {
      f4 ov = o[n];
      for (int r = 0; r < 4; ++r) ov[r] *= scl[r];
      o[n] = ov;
    }

    // PV: P[16x64] @ V[64x64], V^T fragments direct from global
    b8 pf0 = *(const b8*)&Pl[w][lr * PST + lg * 8];
    b8 pf1 = *(const b8*)&Pl[w][lr * PST + 32 + lg * 8];
    const u16* vp = VTb + base + kv0;
    for (int n = 0; n < 4; ++n) {
      b8 vf0 = *(const b8*)(vp + (size_t)(n * 16 + lr) * SS + lg * 8);
      b8 vf1 = *(const b8*)(vp + (size_t)(n * 16 + lr) * SS + 32 + lg * 8);
      o[n] = __builtin_amdgcn_mfma_f32_16x16x32_bf16(pf0, vf0, o[n], 0, 0, 0);
      o[n] = __builtin_amdgcn_mfma_f32_16x16x32_bf16(pf1, vf1, o[n], 0, 0, 0);
    }
  }

  // epilogue -> AO [B,S,H*D] bf16
  for (int n = 0; n < 4; ++n)
    for (int r = 0; r < 4; ++r) {
      int qgr = qg + r;
      int d = n * 16 + lr;
      float val = o[n][r] / lsum[r];
      AO[((size_t)b * SS + qgr) * (HH * DD) + h * DD + d] = f2b(val);
    }
}

// ---------------- launch ----------------
extern "C" void kernel_launch(void* const* d_in, const int* in_sizes, int n_in,
                              void* d_out, int out_size, void* d_ws, size_t ws_size,
                              hipStream_t stream) {
  const float* x  = (const float*)d_in[0];
  const float* Wq = (const float*)d_in[1];
  const float* Wk = (const float*)d_in[2];
  const float* Wv = (const float*)d_in[3];
  const float* bq = (const float*)d_in[4];
  const float* bk = (const float*)d_in[5];
  const float* bv = (const float*)d_in[6];
  const float* Wo = (const float*)d_in[7];
  const float* bo = (const float*)d_in[8];

  char* ws = (char*)d_ws;
  u16* xb  = (u16*)(ws);                       // 8 MiB (aliased later by AO)
  u16* Wt  = (u16*)(ws + ((size_t)8 << 20));   // 6 MiB
  u16* Wot = (u16*)(ws + ((size_t)14 << 20));  // 2 MiB
  u16* Qw  = (u16*)(ws + ((size_t)16 << 20));  // 8 MiB
  u16* Kw  = (u16*)(ws + ((size_t)24 << 20));  // 8 MiB
  u16* VTw = (u16*)(ws + ((size_t)32 << 20));  // 8 MiB, layout [B,H,D,S]
  u16* AO  = xb;  // safe: fattn runs entirely after gemm128<0> consumed xb

  castx<<<1024, 256, 0, stream>>>(x, xb);
  transW<<<dim3(16, 48), 256, 0, stream>>>(Wq, Wk, Wv, Wt);
  transWo<<<dim3(16, 16), 256, 0, stream>>>(Wo, Wot);
  gemm128<0><<<dim3(24, 32), 256, 0, stream>>>(xb, Wt, Qw, Kw, VTw, bq, bk, bv,
                                               nullptr, nullptr);
  fattn<<<dim3(32, 32), 256, 0, stream>>>(Qw, Kw, VTw, AO);
  gemm128<1><<<dim3(8, 32), 256, 0, stream>>>(AO, Wot, nullptr, nullptr, nullptr,
                                              nullptr, nullptr, nullptr,
                                              (float*)d_out, bo);
}

// Round 4
// 238.614 us; speedup vs baseline: 1.6270x; 1.6270x over previous
//
#include <hip/hip_runtime.h>

#define BB 2
#define SS 2048
#define EE 1024
#define HH 16
#define DD 64

typedef unsigned short u16;
typedef float f4 __attribute__((ext_vector_type(4)));
typedef __bf16 b8 __attribute__((ext_vector_type(8)));
typedef short s8i __attribute__((ext_vector_type(8)));
typedef u16 u16x4 __attribute__((ext_vector_type(4)));

__device__ inline u16 f2b(float f) {
  unsigned u = __builtin_bit_cast(unsigned, f);
  unsigned r = (u + 0x7fffu + ((u >> 16) & 1u)) >> 16;
  return (u16)r;
}

// ---------------- prep kernels ----------------
__global__ void castx(const float* __restrict__ x, u16* __restrict__ xb) {
  const int N4 = BB * SS * EE / 4;
  for (int i = blockIdx.x * blockDim.x + threadIdx.x; i < N4;
       i += gridDim.x * blockDim.x) {
    f4 v = ((const f4*)x)[i];
    u16x4 o;
    for (int j = 0; j < 4; ++j) o[j] = f2b(v[j]);
    ((u16x4*)xb)[i] = o;
  }
}

// Wt[(qkv*1024 + h*64 + d)][e] = Wqkv[h][e][d]  — LDS tile transpose
__global__ __launch_bounds__(256) void transW(const float* __restrict__ Wq,
                                              const float* __restrict__ Wk,
                                              const float* __restrict__ Wv,
                                              u16* __restrict__ Wt) {
  __shared__ float tile[64][65];
  int t = threadIdx.x;
  int e0 = blockIdx.x * 64;
  int y = blockIdx.y;          // 0..47
  int qkv = y >> 4, h = y & 15;
  const float* W = (qkv == 0) ? Wq : (qkv == 1) ? Wk : Wv;
  for (int p = 0; p < 16; ++p) {
    int i = p * 4 + (t >> 6), d = t & 63;
    tile[i][d] = W[((size_t)h * EE + e0 + i) * DD + d];
  }
  __syncthreads();
  for (int p = 0; p < 16; ++p) {
    int d = p * 4 + (t >> 6), i = t & 63;
    Wt[((size_t)qkv * 1024 + h * 64 + d) * EE + e0 + i] = f2b(tile[i][d]);
  }
}

// Wot[c][e] = Wo[e][c]
__global__ __launch_bounds__(256) void transWo(const float* __restrict__ Wo,
                                               u16* __restrict__ Wot) {
  __shared__ float tile[64][65];
  int t = threadIdx.x;
  int e0 = blockIdx.x * 64, c0 = blockIdx.y * 64;
  for (int p = 0; p < 16; ++p) {
    int i = p * 4 + (t >> 6), j = t & 63;
    tile[i][j] = Wo[(size_t)(e0 + i) * (HH * DD) + c0 + j];
  }
  __syncthreads();
  for (int p = 0; p < 16; ++p) {
    int j = p * 4 + (t >> 6), i = t & 63;
    Wot[(size_t)(c0 + j) * EE + e0 + i] = f2b(tile[i][j]);
  }
}

// ---------------- 128x128 bf16 MFMA GEMM, global_load_lds staging -------------
// MODE 0: C -> Q(scaled 1/8)/K bf16 [B,H,S,D], V bf16 [B,H,D,S] (transposed)
// MODE 1: C -> fp32 out [4096,1024] + bo
template <int MODE>
__global__ __launch_bounds__(256) void gemm128(
    const u16* __restrict__ A, const u16* __restrict__ Bm,
    u16* __restrict__ Qo, u16* __restrict__ Ko, u16* __restrict__ Vo,
    const float* __restrict__ bq, const float* __restrict__ bk,
    const float* __restrict__ bv,
    float* __restrict__ Co, const float* __restrict__ bo) {
  const int K = 1024;
  __shared__ u16 As[128 * 32];
  __shared__ u16 Bs[128 * 32];
  int t = threadIdx.x;
  int lane = t & 63, w = t >> 6;
  int wr = w >> 1, wc = w & 1;
  int lr = lane & 15, lg = lane >> 4;
  int m0 = blockIdx.y * 128, n0 = blockIdx.x * 128;

  f4 acc[4][4];
  const f4 z4 = {0.f, 0.f, 0.f, 0.f};
  for (int mi = 0; mi < 4; ++mi)
    for (int ni = 0; ni < 4; ++ni) acc[mi][ni] = z4;

  // staging map: 16B chunk c at LDS byte c*16; c = row*4 + slot, row-major [128][32]
  int r0 = t >> 2, s0 = t & 3;
  const u16* ga0 = A + (size_t)(m0 + r0) * K + s0 * 8;
  const u16* gb0 = Bm + (size_t)(n0 + r0) * K + s0 * 8;
  u16* la0 = As + w * 512;        // wave-uniform base, lane*16B implicit
  u16* la1 = As + 2048 + w * 512;
  u16* lb0 = Bs + w * 512;
  u16* lb1 = Bs + 2048 + w * 512;

  for (int ks = 0; ks < K / 32; ++ks) {
    int k0 = ks * 32;
    __builtin_amdgcn_global_load_lds(
        (const __attribute__((address_space(1))) void*)(ga0 + k0),
        (__attribute__((address_space(3))) void*)la0, 16, 0, 0);
    __builtin_amdgcn_global_load_lds(
        (const __attribute__((address_space(1))) void*)(ga0 + 64 * K + k0),
        (__attribute__((address_space(3))) void*)la1, 16, 0, 0);
    __builtin_amdgcn_global_load_lds(
        (const __attribute__((address_space(1))) void*)(gb0 + k0),
        (__attribute__((address_space(3))) void*)lb0, 16, 0, 0);
    __builtin_amdgcn_global_load_lds(
        (const __attribute__((address_space(1))) void*)(gb0 + 64 * K + k0),
        (__attribute__((address_space(3))) void*)lb1, 16, 0, 0);
    __syncthreads();
    b8 af[4], bf[4];
    for (int mi = 0; mi < 4; ++mi)
      af[mi] = *(const b8*)&As[(wr * 64 + mi * 16 + lr) * 32 + lg * 8];
    for (int ni = 0; ni < 4; ++ni)
      bf[ni] = *(const b8*)&Bs[(wc * 64 + ni * 16 + lr) * 32 + lg * 8];
    for (int mi = 0; mi < 4; ++mi)
      for (int ni = 0; ni < 4; ++ni)
        acc[mi][ni] = __builtin_amdgcn_mfma_f32_16x16x32_bf16(af[mi], bf[ni],
                                                              acc[mi][ni], 0, 0, 0);
    __syncthreads();
  }

  for (int mi = 0; mi < 4; ++mi)
    for (int ni = 0; ni < 4; ++ni)
      for (int r = 0; r < 4; ++r) {
        int m_g = m0 + wr * 64 + mi * 16 + lg * 4 + r;
        int n_g = n0 + wc * 64 + ni * 16 + lr;
        float v = acc[mi][ni][r];
        if (MODE == 0) {
          int qkv = n_g >> 10, hd = n_g & 1023;
          const float* bias = (qkv == 0) ? bq : (qkv == 1) ? bk : bv;
          v += bias[hd];
          int b = m_g >> 11, s = m_g & 2047;
          int h = hd >> 6, d = hd & 63;
          if (qkv == 0) {
            Qo[(((size_t)b * HH + h) * SS + s) * DD + d] = f2b(v * 0.125f);
          } else if (qkv == 1) {
            Ko[(((size_t)b * HH + h) * SS + s) * DD + d] = f2b(v);
          } else {  // V stored transposed: [B,H,D,S]
            Vo[(((size_t)b * HH + h) * DD + d) * SS + s] = f2b(v);
          }
        } else {
          Co[(size_t)m_g * 1024 + n_g] = v + bo[n_g];
        }
      }
}

// ---------------- flash attention (causal) -----------------------------------
// Paired q-tiles for perfect balance: block p does qt=31-p then qt=p (33 tiles).
// K double-buffered in LDS (stride 72 -> conflict-free b128), async reg-staged.
// V prefetched to regs per-wave from VT [B,H,D,S]. One barrier per KV tile.
#define KST 72  // K LDS row stride (u16)
#define PST 72  // P LDS row stride (u16)
__global__ __launch_bounds__(256) void fattn(const u16* __restrict__ Qb,
                                             const u16* __restrict__ Kb,
                                             const u16* __restrict__ VTb,
                                             u16* __restrict__ AO) {
  __shared__ u16 Kl[2][64 * KST];
  __shared__ u16 Pl[4][16 * PST];

  int t = threadIdx.x, lane = t & 63, w = t >> 6;
  int lr = lane & 15, lg = lane >> 4;
  int bh = blockIdx.y;
  int b = bh >> 4, h = bh & 15;
  size_t base = (size_t)bh * SS * DD;

  // K staging map: thread covers rows r0 (chunks of 16B), conflict-free on 72-stride
  int r0 = t >> 2, s0 = t & 3;
  u16* kl0 = &Kl[0][r0 * KST + s0 * 8];
  u16* kl1 = &Kl[1][r0 * KST + s0 * 8];
  const u16* kg = Kb + base + (size_t)r0 * DD + s0 * 8;

  for (int half = 0; half < 2; ++half) {
    int qt = half ? blockIdx.x : 31 - blockIdx.x;
    int qbase = qt * 64;
    int nt = qt + 1;

    const u16* qp = Qb + base + (size_t)(qbase + w * 16 + lr) * DD;
    b8 qf0 = *(const b8*)(qp + lg * 8);
    b8 qf1 = *(const b8*)(qp + 32 + lg * 8);

    const f4 z4 = {0.f, 0.f, 0.f, 0.f};
    f4 o[4];
    for (int i = 0; i < 4; ++i) o[i] = z4;
    float mrow[4], lsum[4];
    for (int r = 0; r < 4; ++r) { mrow[r] = -1e30f; lsum[r] = 0.f; }
    int qg = qbase + w * 16 + lg * 4;

    // prologue: stage K tile 0 into Kl[0]
    {
      s8i k0v = *(const s8i*)(kg);
      s8i k1v = *(const s8i*)(kg + 32);
      *(s8i*)kl0 = k0v;
      *(s8i*)(kl0 + 32) = k1v;
    }
    __syncthreads();

    for (int kt = 0; kt < nt; ++kt) {
      int cur = kt & 1;
      int kv0 = kt * 64;
      const u16* vp = VTb + base + kv0 + (size_t)lr * SS;

      // prefetch V fragments for THIS tile into regs (consumed at PV)
      b8 vr[8];
      for (int n = 0; n < 4; ++n) {
        vr[2 * n] = *(const b8*)(vp + (size_t)(n * 16) * SS + lg * 8);
        vr[2 * n + 1] = *(const b8*)(vp + (size_t)(n * 16) * SS + 32 + lg * 8);
      }
      // prefetch K tile kt+1 into regs (written to LDS at end of iter)
      s8i nk0, nk1;
      bool more = (kt + 1 < nt);
      if (more) {
        const u16* kgn = kg + (size_t)(kv0 + 64) * DD;
        nk0 = *(const s8i*)(kgn);
        nk1 = *(const s8i*)(kgn + 32);
      }

      // S = Q K^T from Kl[cur]
      f4 sa[4];
      for (int n = 0; n < 4; ++n) sa[n] = z4;
      for (int n = 0; n < 4; ++n) {
        b8 kf0 = *(const b8*)&Kl[cur][(n * 16 + lr) * KST + lg * 8];
        b8 kf1 = *(const b8*)&Kl[cur][(n * 16 + lr) * KST + 32 + lg * 8];
        sa[n] = __builtin_amdgcn_mfma_f32_16x16x32_bf16(qf0, kf0, sa[n], 0, 0, 0);
        sa[n] = __builtin_amdgcn_mfma_f32_16x16x32_bf16(qf1, kf1, sa[n], 0, 0, 0);
      }

      // online softmax
      bool diag = (kt == nt - 1);
      float scl[4];
      for (int r = 0; r < 4; ++r) {
        float v0 = sa[0][r], v1 = sa[1][r], v2 = sa[2][r], v3 = sa[3][r];
        if (diag) {
          int q = qg + r;
          if (kv0 + lr > q) v0 = -1e30f;
          if (kv0 + 16 + lr > q) v1 = -1e30f;
          if (kv0 + 32 + lr > q) v2 = -1e30f;
          if (kv0 + 48 + lr > q) v3 = -1e30f;
        }
        float mx = fmaxf(fmaxf(v0, v1), fmaxf(v2, v3));
        mx = fmaxf(mx, __shfl_xor(mx, 1));
        mx = fmaxf(mx, __shfl_xor(mx, 2));
        mx = fmaxf(mx, __shfl_xor(mx, 4));
        mx = fmaxf(mx, __shfl_xor(mx, 8));
        float mn = fmaxf(mrow[r], mx);
        float sc = __expf(mrow[r] - mn);
        float p0 = __expf(v0 - mn), p1 = __expf(v1 - mn);
        float p2 = __expf(v2 - mn), p3 = __expf(v3 - mn);
        float ps = (p0 + p1) + (p2 + p3);
        ps += __shfl_xor(ps, 1);
        ps += __shfl_xor(ps, 2);
        ps += __shfl_xor(ps, 4);
        ps += __shfl_xor(ps, 8);
        lsum[r] = lsum[r] * sc + ps;
        mrow[r] = mn;
        scl[r] = sc;
        int prow = (lg * 4 + r) * PST;
        Pl[w][prow + lr] = f2b(p0);
        Pl[w][prow + 16 + lr] = f2b(p1);
        Pl[w][prow + 32 + lr] = f2b(p2);
        Pl[w][prow + 48 + lr] = f2b(p3);
      }
      for (int n = 0; n < 4; ++n) {
        f4 ov = o[n];
        for (int r = 0; r < 4; ++r) ov[r] *= scl[r];
        o[n] = ov;
      }

      // PV: P[16x64] @ V[64x64] using prefetched V regs
      b8 pf0 = *(const b8*)&Pl[w][lr * PST + lg * 8];
      b8 pf1 = *(const b8*)&Pl[w][lr * PST + 32 + lg * 8];
      for (int n = 0; n < 4; ++n) {
        o[n] = __builtin_amdgcn_mfma_f32_16x16x32_bf16(pf0, vr[2 * n], o[n], 0, 0, 0);
        o[n] = __builtin_amdgcn_mfma_f32_16x16x32_bf16(pf1, vr[2 * n + 1], o[n], 0, 0, 0);
      }

      // write next K tile into the other buffer, then one barrier
      if (more) {
        u16* kln = cur ? kl0 : kl1;
        *(s8i*)kln = nk0;
        *(s8i*)(kln + 32) = nk1;
      }
      __syncthreads();
    }

    // epilogue -> AO [B,S,H*D] bf16
    for (int n = 0; n < 4; ++n)
      for (int r = 0; r < 4; ++r) {
        int qgr = qg + r;
        int d = n * 16 + lr;
        float val = o[n][r] / lsum[r];
        AO[((size_t)b * SS + qgr) * (HH * DD) + h * DD + d] = f2b(val);
      }
    __syncthreads();  // Kl reuse safety between halves
  }
}

// ---------------- launch ----------------
extern "C" void kernel_launch(void* const* d_in, const int* in_sizes, int n_in,
                              void* d_out, int out_size, void* d_ws, size_t ws_size,
                              hipStream_t stream) {
  const float* x  = (const float*)d_in[0];
  const float* Wq = (const float*)d_in[1];
  const float* Wk = (const float*)d_in[2];
  const float* Wv = (const float*)d_in[3];
  const float* bq = (const float*)d_in[4];
  const float* bk = (const float*)d_in[5];
  const float* bv = (const float*)d_in[6];
  const float* Wo = (const float*)d_in[7];
  const float* bo = (const float*)d_in[8];

  char* ws = (char*)d_ws;
  u16* xb  = (u16*)(ws);                       // 8 MiB (aliased later by AO)
  u16* Wt  = (u16*)(ws + ((size_t)8 << 20));   // 6 MiB
  u16* Wot = (u16*)(ws + ((size_t)14 << 20));  // 2 MiB
  u16* Qw  = (u16*)(ws + ((size_t)16 << 20));  // 8 MiB
  u16* Kw  = (u16*)(ws + ((size_t)24 << 20));  // 8 MiB
  u16* VTw = (u16*)(ws + ((size_t)32 << 20));  // 8 MiB, layout [B,H,D,S]
  u16* AO  = xb;  // safe: fattn runs entirely after gemm128<0> consumed xb

  castx<<<1024, 256, 0, stream>>>(x, xb);
  transW<<<dim3(16, 48), 256, 0, stream>>>(Wq, Wk, Wv, Wt);
  transWo<<<dim3(16, 16), 256, 0, stream>>>(Wo, Wot);
  gemm128<0><<<dim3(24, 32), 256, 0, stream>>>(xb, Wt, Qw, Kw, VTw, bq, bk, bv,
                                               nullptr, nullptr);
  fattn<<<dim3(16, 32), 256, 0, stream>>>(Qw, Kw, VTw, AO);
  gemm128<1><<<dim3(8, 32), 256, 0, stream>>>(AO, Wot, nullptr, nullptr, nullptr,
                                              nullptr, nullptr, nullptr,
                                              (float*)d_out, bo);
}

// Round 6
// 221.257 us; speedup vs baseline: 1.7546x; 1.0784x over previous
//
#include <hip/hip_runtime.h>

#define BB 2
#define SS 2048
#define EE 1024
#define HH 16
#define DD 64

typedef unsigned short u16;
typedef float f4 __attribute__((ext_vector_type(4)));
typedef __bf16 b8 __attribute__((ext_vector_type(8)));
typedef short s8i __attribute__((ext_vector_type(8)));
typedef u16 u16x4 __attribute__((ext_vector_type(4)));

__device__ inline u16 f2b(float f) {
  unsigned u = __builtin_bit_cast(unsigned, f);
  unsigned r = (u + 0x7fffu + ((u >> 16) & 1u)) >> 16;
  return (u16)r;
}

// ---------------- fused prep: castx | transW | transWo ----------------
__global__ __launch_bounds__(256) void prep(const float* __restrict__ x,
                                            const float* __restrict__ Wq,
                                            const float* __restrict__ Wk,
                                            const float* __restrict__ Wv,
                                            const float* __restrict__ Wo,
                                            u16* __restrict__ xb,
                                            u16* __restrict__ Wt,
                                            u16* __restrict__ Wot) {
  int bid = blockIdx.x;
  int t = threadIdx.x;
  if (bid < 1024) {
    // castx: 1M f4 chunks over 1024 blocks x 256 thr x 4
    int i0 = bid * 256 + t;
    for (int j = 0; j < 4; ++j) {
      int i = i0 + j * 262144;
      f4 v = ((const f4*)x)[i];
      u16x4 o;
      for (int k2 = 0; k2 < 4; ++k2) o[k2] = f2b(v[k2]);
      ((u16x4*)xb)[i] = o;
    }
  } else if (bid < 1792) {
    // transW: Wt[(qkv*1024 + h*64 + d)][e] = Wqkv[h][e][d]
    __shared__ float tile[64][65];
    int z = bid - 1024;
    int y = z >> 4;                  // 0..47
    int e0 = (z & 15) * 64;
    int qkv = y >> 4, h = y & 15;
    const float* W = (qkv == 0) ? Wq : (qkv == 1) ? Wk : Wv;
    for (int p = 0; p < 16; ++p) {
      int i = p * 4 + (t >> 6), d = t & 63;
      tile[i][d] = W[((size_t)h * EE + e0 + i) * DD + d];
    }
    __syncthreads();
    for (int p = 0; p < 16; ++p) {
      int d = p * 4 + (t >> 6), i = t & 63;
      Wt[((size_t)qkv * 1024 + h * 64 + d) * EE + e0 + i] = f2b(tile[i][d]);
    }
  } else {
    // transWo: Wot[c][e] = Wo[e*1024+c]  (so Wot[n][k=c] = Wo_matrix[c][n])
    __shared__ float tile2[64][65];
    int z = bid - 1792;              // 0..255
    int e0 = (z & 15) * 64, c0 = (z >> 4) * 64;
    for (int p = 0; p < 16; ++p) {
      int i = p * 4 + (t >> 6), j = t & 63;
      tile2[i][j] = Wo[(size_t)(e0 + i) * (HH * DD) + c0 + j];
    }
    __syncthreads();
    for (int p = 0; p < 16; ++p) {
      int j = p * 4 + (t >> 6), i = t & 63;
      Wot[(size_t)(c0 + j) * EE + e0 + i] = f2b(tile2[i][j]);
    }
  }
}

// ---------------- 128x128 bf16 MFMA GEMM, global_load_lds staging -------------
// MODE 0: C -> Q(scaled log2e/8)/K bf16 [B,H,S,D], V bf16 [B,H,D,S] (transposed)
// MODE 1: C -> fp32 out [4096,1024] + bo
template <int MODE>
__global__ __launch_bounds__(256) void gemm128(
    const u16* __restrict__ A, const u16* __restrict__ Bm,
    u16* __restrict__ Qo, u16* __restrict__ Ko, u16* __restrict__ Vo,
    const float* __restrict__ bq, const float* __restrict__ bk,
    const float* __restrict__ bv,
    float* __restrict__ Co, const float* __restrict__ bo) {
  const int K = 1024;
  __shared__ u16 As[128 * 32];
  __shared__ u16 Bs[128 * 32];
  int t = threadIdx.x;
  int lane = t & 63, w = t >> 6;
  int wr = w >> 1, wc = w & 1;
  int lr = lane & 15, lg = lane >> 4;
  int m0 = blockIdx.y * 128, n0 = blockIdx.x * 128;

  f4 acc[4][4];
  const f4 z4 = {0.f, 0.f, 0.f, 0.f};
  for (int mi = 0; mi < 4; ++mi)
    for (int ni = 0; ni < 4; ++ni) acc[mi][ni] = z4;

  int r0 = t >> 2, s0 = t & 3;
  const u16* ga0 = A + (size_t)(m0 + r0) * K + s0 * 8;
  const u16* gb0 = Bm + (size_t)(n0 + r0) * K + s0 * 8;
  u16* la0 = As + w * 512;
  u16* la1 = As + 2048 + w * 512;
  u16* lb0 = Bs + w * 512;
  u16* lb1 = Bs + 2048 + w * 512;

  for (int ks = 0; ks < K / 32; ++ks) {
    int k0 = ks * 32;
    __builtin_amdgcn_global_load_lds(
        (const __attribute__((address_space(1))) void*)(ga0 + k0),
        (__attribute__((address_space(3))) void*)la0, 16, 0, 0);
    __builtin_amdgcn_global_load_lds(
        (const __attribute__((address_space(1))) void*)(ga0 + 64 * K + k0),
        (__attribute__((address_space(3))) void*)la1, 16, 0, 0);
    __builtin_amdgcn_global_load_lds(
        (const __attribute__((address_space(1))) void*)(gb0 + k0),
        (__attribute__((address_space(3))) void*)lb0, 16, 0, 0);
    __builtin_amdgcn_global_load_lds(
        (const __attribute__((address_space(1))) void*)(gb0 + 64 * K + k0),
        (__attribute__((address_space(3))) void*)lb1, 16, 0, 0);
    __syncthreads();
    b8 af[4], bf[4];
    for (int mi = 0; mi < 4; ++mi)
      af[mi] = *(const b8*)&As[(wr * 64 + mi * 16 + lr) * 32 + lg * 8];
    for (int ni = 0; ni < 4; ++ni)
      bf[ni] = *(const b8*)&Bs[(wc * 64 + ni * 16 + lr) * 32 + lg * 8];
    for (int mi = 0; mi < 4; ++mi)
      for (int ni = 0; ni < 4; ++ni)
        acc[mi][ni] = __builtin_amdgcn_mfma_f32_16x16x32_bf16(af[mi], bf[ni],
                                                              acc[mi][ni], 0, 0, 0);
    __syncthreads();
  }

  const float QSC = 0.18033688011112042f;  // (1/8) * log2(e)
  for (int mi = 0; mi < 4; ++mi)
    for (int ni = 0; ni < 4; ++ni)
      for (int r = 0; r < 4; ++r) {
        int m_g = m0 + wr * 64 + mi * 16 + lg * 4 + r;
        int n_g = n0 + wc * 64 + ni * 16 + lr;
        float v = acc[mi][ni][r];
        if (MODE == 0) {
          int qkv = n_g >> 10, hd = n_g & 1023;
          const float* bias = (qkv == 0) ? bq : (qkv == 1) ? bk : bv;
          v += bias[hd];
          int b = m_g >> 11, s = m_g & 2047;
          int h = hd >> 6, d = hd & 63;
          if (qkv == 0) {
            Qo[(((size_t)b * HH + h) * SS + s) * DD + d] = f2b(v * QSC);
          } else if (qkv == 1) {
            Ko[(((size_t)b * HH + h) * SS + s) * DD + d] = f2b(v);
          } else {  // V stored transposed: [B,H,D,S]
            Vo[(((size_t)b * HH + h) * DD + d) * SS + s] = f2b(v);
          }
        } else {
          Co[(size_t)m_g * 1024 + n_g] = v + bo[n_g];
        }
      }
}

// ---------------- flash attention (causal) -----------------------------------
// Paired q-tiles: block p does qt=31-p then qt=p (33 tiles each -> balanced).
// K and V double-buffered in LDS (stride 72, conflict-free b128), reg-staged.
// Softmax in exp2 domain (Q pre-scaled by log2e/8); per-tile max update (R4-
// proven form); per-lane partial lsum reduced once in the epilogue.
#define KST 72
#define PST 72
__global__ __launch_bounds__(256) void fattn(const u16* __restrict__ Qb,
                                             const u16* __restrict__ Kb,
                                             const u16* __restrict__ VTb,
                                             u16* __restrict__ AO) {
  __shared__ u16 Kl[2][64 * KST];
  __shared__ u16 Vl[2][64 * KST];  // [d][kv], stride 72
  __shared__ u16 Pl[4][16 * PST];

  int t = threadIdx.x, lane = t & 63, w = t >> 6;
  int lr = lane & 15, lg = lane >> 4;
  int bh = blockIdx.y;
  int b = bh >> 4, h = bh & 15;
  size_t base = (size_t)bh * SS * DD;

  int r0 = t >> 2, s0 = t & 3;
  u16* kl0 = &Kl[0][r0 * KST + s0 * 8];
  u16* kl1 = &Kl[1][r0 * KST + s0 * 8];
  u16* vl0 = &Vl[0][r0 * KST + s0 * 8];
  u16* vl1 = &Vl[1][r0 * KST + s0 * 8];
  const u16* kg = Kb + base + (size_t)r0 * DD + s0 * 8;   // K row r0(kv), chunk
  const u16* vg = VTb + base + (size_t)r0 * SS + s0 * 8;  // VT row r0(d), + kv0

  for (int half = 0; half < 2; ++half) {
    int qt = half ? blockIdx.x : 31 - blockIdx.x;
    int qbase = qt * 64;
    int nt = qt + 1;

    const u16* qp = Qb + base + (size_t)(qbase + w * 16 + lr) * DD;
    b8 qf0 = *(const b8*)(qp + lg * 8);
    b8 qf1 = *(const b8*)(qp + 32 + lg * 8);

    const f4 z4 = {0.f, 0.f, 0.f, 0.f};
    f4 o[4];
    for (int i = 0; i < 4; ++i) o[i] = z4;
    float mrow[4], lsum[4];
    for (int r = 0; r < 4; ++r) { mrow[r] = -1e30f; lsum[r] = 0.f; }
    int qg = qbase + w * 16 + lg * 4;

    // prologue: stage K0,V0 into buffer 0
    {
      *(s8i*)kl0 = *(const s8i*)(kg);
      *(s8i*)(kl0 + 32) = *(const s8i*)(kg + 32);
      *(s8i*)vl0 = *(const s8i*)(vg);
      *(s8i*)(vl0 + 32) = *(const s8i*)(vg + 32);
    }
    __syncthreads();

    for (int kt = 0; kt < nt; ++kt) {
      int cur = kt & 1;
      int kv0 = kt * 64;

      // prefetch next K,V tiles into regs (written to LDS at iteration end)
      s8i nk0, nk1, nv0, nv1;
      bool more = (kt + 1 < nt);
      if (more) {
        const u16* kgn = kg + (size_t)(kv0 + 64) * DD;
        const u16* vgn = vg + kv0 + 64;
        nk0 = *(const s8i*)(kgn);
        nk1 = *(const s8i*)(kgn + 32);
        nv0 = *(const s8i*)(vgn);
        nv1 = *(const s8i*)(vgn + 32);
      }

      // S = Q K^T from Kl[cur]  (values are score * log2e)
      f4 sa[4];
      for (int n = 0; n < 4; ++n) sa[n] = z4;
      for (int n = 0; n < 4; ++n) {
        b8 kf0 = *(const b8*)&Kl[cur][(n * 16 + lr) * KST + lg * 8];
        b8 kf1 = *(const b8*)&Kl[cur][(n * 16 + lr) * KST + 32 + lg * 8];
        sa[n] = __builtin_amdgcn_mfma_f32_16x16x32_bf16(qf0, kf0, sa[n], 0, 0, 0);
        sa[n] = __builtin_amdgcn_mfma_f32_16x16x32_bf16(qf1, kf1, sa[n], 0, 0, 0);
      }

      // causal mask on diagonal tile
      if (kt == nt - 1) {
        for (int r = 0; r < 4; ++r) {
          int q = qg + r;
          if (kv0 + lr > q) sa[0][r] = -1e30f;
          if (kv0 + 16 + lr > q) sa[1][r] = -1e30f;
          if (kv0 + 32 + lr > q) sa[2][r] = -1e30f;
          if (kv0 + 48 + lr > q) sa[3][r] = -1e30f;
        }
      }

      // online softmax, exp2 domain, per-tile max update (R4-proven structure)
      float scl[4];
      for (int r = 0; r < 4; ++r) {
        float mx = fmaxf(fmaxf(sa[0][r], sa[1][r]), fmaxf(sa[2][r], sa[3][r]));
        mx = fmaxf(mx, __shfl_xor(mx, 1));
        mx = fmaxf(mx, __shfl_xor(mx, 2));
        mx = fmaxf(mx, __shfl_xor(mx, 4));
        mx = fmaxf(mx, __shfl_xor(mx, 8));
        float mn = fmaxf(mrow[r], mx);
        float sc = __builtin_amdgcn_exp2f(mrow[r] - mn);
        float p0 = __builtin_amdgcn_exp2f(sa[0][r] - mn);
        float p1 = __builtin_amdgcn_exp2f(sa[1][r] - mn);
        float p2 = __builtin_amdgcn_exp2f(sa[2][r] - mn);
        float p3 = __builtin_amdgcn_exp2f(sa[3][r] - mn);
        lsum[r] = lsum[r] * sc + ((p0 + p1) + (p2 + p3));
        mrow[r] = mn;
        scl[r] = sc;
        int prow = (lg * 4 + r) * PST;
        Pl[w][prow + lr] = f2b(p0);
        Pl[w][prow + 16 + lr] = f2b(p1);
        Pl[w][prow + 32 + lr] = f2b(p2);
        Pl[w][prow + 48 + lr] = f2b(p3);
      }
      for (int n = 0; n < 4; ++n) {
        f4 ov = o[n];
        for (int r = 0; r < 4; ++r) ov[r] *= scl[r];
        o[n] = ov;
      }

      // PV: P[16x64] @ V[64x64] from Vl[cur]
      b8 pf0 = *(const b8*)&Pl[w][lr * PST + lg * 8];
      b8 pf1 = *(const b8*)&Pl[w][lr * PST + 32 + lg * 8];
      for (int n = 0; n < 4; ++n) {
        b8 vf0 = *(const b8*)&Vl[cur][(n * 16 + lr) * KST + lg * 8];
        b8 vf1 = *(const b8*)&Vl[cur][(n * 16 + lr) * KST + 32 + lg * 8];
        o[n] = __builtin_amdgcn_mfma_f32_16x16x32_bf16(pf0, vf0, o[n], 0, 0, 0);
        o[n] = __builtin_amdgcn_mfma_f32_16x16x32_bf16(pf1, vf1, o[n], 0, 0, 0);
      }

      // write next tiles to the other buffers, one barrier per iteration
      if (more) {
        u16* kln = cur ? kl0 : kl1;
        u16* vln = cur ? vl0 : vl1;
        *(s8i*)kln = nk0;
        *(s8i*)(kln + 32) = nk1;
        *(s8i*)vln = nv0;
        *(s8i*)(vln + 32) = nv1;
      }
      __syncthreads();
    }

    // epilogue: reduce partial lsum across lr, write AO [B,S,H*D]
    float rl[4];
    for (int r = 0; r < 4; ++r) {
      float s = lsum[r];
      s += __shfl_xor(s, 1);
      s += __shfl_xor(s, 2);
      s += __shfl_xor(s, 4);
      s += __shfl_xor(s, 8);
      rl[r] = 1.f / s;
    }
    for (int n = 0; n < 4; ++n)
      for (int r = 0; r < 4; ++r) {
        int qgr = qg + r;
        int d = n * 16 + lr;
        AO[((size_t)b * SS + qgr) * (HH * DD) + h * DD + d] = f2b(o[n][r] * rl[r]);
      }
    __syncthreads();  // LDS reuse safety between halves
  }
}

// ---------------- launch ----------------
extern "C" void kernel_launch(void* const* d_in, const int* in_sizes, int n_in,
                              void* d_out, int out_size, void* d_ws, size_t ws_size,
                              hipStream_t stream) {
  const float* x  = (const float*)d_in[0];
  const float* Wq = (const float*)d_in[1];
  const float* Wk = (const float*)d_in[2];
  const float* Wv = (const float*)d_in[3];
  const float* bq = (const float*)d_in[4];
  const float* bk = (const float*)d_in[5];
  const float* bv = (const float*)d_in[6];
  const float* Wo = (const float*)d_in[7];
  const float* bo = (const float*)d_in[8];

  char* ws = (char*)d_ws;
  u16* xb  = (u16*)(ws);                       // 8 MiB (aliased later by AO)
  u16* Wt  = (u16*)(ws + ((size_t)8 << 20));   // 6 MiB
  u16* Wot = (u16*)(ws + ((size_t)14 << 20));  // 2 MiB
  u16* Qw  = (u16*)(ws + ((size_t)16 << 20));  // 8 MiB
  u16* Kw  = (u16*)(ws + ((size_t)24 << 20));  // 8 MiB
  u16* VTw = (u16*)(ws + ((size_t)32 << 20));  // 8 MiB, layout [B,H,D,S]
  u16* AO  = xb;  // safe: fattn runs entirely after gemm128<0> consumed xb

  prep<<<2048, 256, 0, stream>>>(x, Wq, Wk, Wv, Wo, xb, Wt, Wot);
  gemm128<0><<<dim3(24, 32), 256, 0, stream>>>(xb, Wt, Qw, Kw, VTw, bq, bk, bv,
                                               nullptr, nullptr);
  fattn<<<dim3(16, 32), 256, 0, stream>>>(Qw, Kw, VTw, AO);
  gemm128<1><<<dim3(8, 32), 256, 0, stream>>>(AO, Wot, nullptr, nullptr, nullptr,
                                              nullptr, nullptr, nullptr,
                                              (float*)d_out, bo);
}